// Round 13
// baseline (37.908 us; speedup 1.0000x reference)
//
#include <hip/hip_runtime.h>
#include <math.h>
#include <stdint.h>

// NonLinearLayer: piecewise-quadratic CDF flow on a geometric mesh.
// x:(N,16) f32, pdj:(N,1), sldj:(N,1), log_p:(63,16), mesh_norm:(65,), elmt_size:(64,)
// out = concat(x_out (N*16), pdj_out (N), sldj_out (N))
//
// R13 = R8 (best clean structure, 32.8us) + NON-TEMPORAL coalesced stores.
// Cache theory: the kernel's own 74MB allocating write stream evicts ~35MB of
// x from L3 every dispatch (evidence: 302MB NT fill doesn't flush x residency,
// yet FETCH=37MB ~= half the read set). NT stores skip L3 allocation so x
// stays fully resident across replays. R7's NT failure was the 64B/lane
// layout (partial-line writes, 2.2x amplification); R8's lane-interleaved
// layout fully covers every line, so NT streams cleanly.
// Decisive: FETCH 37 -> <=12MB, WRITE stays ~74MB, dur -> 27-30.

namespace {
constexpr int DIM = 16;
constexpr int ME  = 64;
constexpr float BOUNDF = 50.0f;
// K1 = 0.2/one_step = 0.02*(1.2^32-1);  INV_L2R = 1/log2(1.2)
constexpr float K1      = 6.8164378f;
constexpr float INV_L2R = 3.8017840f;
constexpr int NBIN = 66;                        // sentinel 0, real 1..64, sentinel 65
constexpr int ROWF = 68;                        // floats per row: 16 dims * 4 + pad
constexpr int COEF_FLOATS = NBIN * ROWF;        // 4488
constexpr int EP_BASE = COEF_FLOATS - 63 * DIM; // transient exp(log_p) scratch
}

typedef float f32x4 __attribute__((ext_vector_type(4)));

__global__ __launch_bounds__(256) void nll_kernel(
    const float* __restrict__ x,
    const float* __restrict__ pdj,
    const float* __restrict__ sldj,
    const float* __restrict__ log_p,
    const float* __restrict__ mesh_norm,
    float* __restrict__ out,
    int npts, int npairs)
{
  __shared__ __align__(16) float co[COEF_FLOATS];
  __shared__ float s_mesh[ME + 1];

  const int tid = threadIdx.x;

  // ---- setup 1: parallel loads + exp ----
  if (tid <= ME) s_mesh[tid] = mesh_norm[tid];
  for (int i = tid; i < 63 * DIM; i += 256)
    co[EP_BASE + i] = __expf(log_p[i]);
  __syncthreads();

  // ---- setup 2a: stash ep columns in regs (scratch overwritten in 2b) ----
  const int wv = tid >> 6, lane = tid & 63;
  float epv[4];
#pragma unroll
  for (int i = 0; i < 4; ++i)
    epv[i] = (lane < 63) ? co[EP_BASE + lane * DIM + (4 * wv + i)] : 0.f;
  const float mj  = s_mesh[lane];
  const float mj1 = s_mesh[lane + 1];
  const float mj2 = s_mesh[(lane + 2 > ME) ? ME : (lane + 2)];
  const float es0 = s_mesh[1] - s_mesh[0];
  __syncthreads();

  // ---- setup 2b: wave-parallel normalize + prefix scan, 4 dims/wave.
  //      lane l writes table row l+1 (row = searchsorted k). ----
  const float h = mj1 - mj;
#pragma unroll
  for (int i = 0; i < 4; ++i) {
    const int d = 4 * wv + i;
    const float ep = epv[i];
    float ss = (lane < 63) ? ep * (mj2 - mj) : 0.f;
    ss += __shfl_xor(ss, 1);  ss += __shfl_xor(ss, 2);  ss += __shfl_xor(ss, 4);
    ss += __shfl_xor(ss, 8);  ss += __shfl_xor(ss, 16); ss += __shfl_xor(ss, 32);
    const float scale = (1.0f - es0) / (0.5f * ss);
    const float cur = (lane < 63) ? ep * scale : 1.0f;   // pdf_norm[lane+1]
    float prev = __shfl_up(cur, 1);                       // pdf_norm[lane]
    if (lane == 0) prev = 1.0f;
    const float cell = (prev + cur) * 0.5f * h;
    float v = cell, o;
    o = __shfl_up(v, 1);  if (lane >= 1)  v += o;
    o = __shfl_up(v, 2);  if (lane >= 2)  v += o;
    o = __shfl_up(v, 4);  if (lane >= 4)  v += o;
    o = __shfl_up(v, 8);  if (lane >= 8)  v += o;
    o = __shfl_up(v, 16); if (lane >= 16) v += o;
    o = __shfl_up(v, 32); if (lane >= 32) v += o;
    const float F = v - cell;                             // exclusive prefix = F_ref[lane]
    const float A = 0.5f * (cur - prev) / h;
    const float B = fmaf(-(A + A), mj, prev);
    const float D = fmaf(mj, fmaf(mj, A, -prev), F);
    *reinterpret_cast<float4*>(&co[(lane + 1) * ROWF + 4 * d]) = make_float4(A, B, D, A + A);
  }
  // sentinel rows 0 and 65: (A,B,D,2A) = (0,1,0,0) -> y=xn, dt=1 exactly
  if (tid < 32) {
    const int row = (tid >> 4) ? (NBIN - 1) : 0;
    const int d = tid & 15;
    *reinterpret_cast<float4*>(&co[row * ROWF + 4 * d]) = make_float4(0.f, 1.f, 0.f, 0.f);
  }
  __syncthreads();

  // ---- main loop: 8 elems (half point) per thread, depth-2 prefetch ----
  const int tpg = gridDim.x * blockDim.x;
  const float4* __restrict__ x4 = reinterpret_cast<const float4*>(x);
  f32x4* __restrict__ out4 = reinterpret_cast<f32x4*>(out);
  const int np16 = npts * DIM;

  int t = blockIdx.x * blockDim.x + tid;
  if (t >= npairs) return;

  // pipeline stage A (current) and B (next)
  float4 a0 = x4[2 * t], a1 = x4[2 * t + 1];
  float aps = (t & 1) ? sldj[t >> 1] : pdj[t >> 1];
  int tB = t + tpg;
  bool hasB = tB < npairs;
  float4 b0, b1; float bps = 0.f;
  if (hasB) {
    b0 = x4[2 * tB]; b1 = x4[2 * tB + 1];
    bps = (tB & 1) ? sldj[tB >> 1] : pdj[tB >> 1];
  }

  while (true) {
    // prefetch stage C (t + 2*tpg)
    const int tC = t + 2 * tpg;
    const bool hasC = tC < npairs;
    float4 c0, c1; float cps = 0.f;
    if (hasC) {
      c0 = x4[2 * tC]; c1 = x4[2 * tC + 1];
      cps = (tC & 1) ? sldj[tC >> 1] : pdj[tC >> 1];
    }

    // ---- compute current (t, a0, a1, aps) ----
    const int p  = t >> 1;
    const int hh = t & 1;                      // half: dims hh*8 .. hh*8+7
    const int dbase = hh << 5;                 // float offset of dim block in a row
    const float vals[8] = {a0.x, a0.y, a0.z, a0.w, a1.x, a1.y, a1.z, a1.w};

    float xn[8];
    int   idx[8];
#pragma unroll
    for (int j = 0; j < 8; ++j) {
      const float val = vals[j];
      xn[j] = fmaf(val, 0.01f, 0.5f);
      const float u = fmaf(fabsf(val), K1, 1.0f);
      const float n = __log2f(u) * INV_L2R;
      int k = 32 + (int)ceilf(copysignf(n, val));   // searchsorted k
      k = k < 0 ? 0 : (k > NBIN - 1 ? NBIN - 1 : k);
      idx[j] = k * ROWF + dbase + (j << 2);
    }

    float4 cf[8];
#pragma unroll
    for (int j = 0; j < 8; ++j)
      cf[j] = *reinterpret_cast<const float4*>(&co[idx[j]]);

    float yv[8], dt[8];
#pragma unroll
    for (int j = 0; j < 8; ++j) {
      const float z = xn[j];
      yv[j] = fmaf(fmaf(z, fmaf(z, cf[j].x, cf[j].y), cf[j].z), 2.0f * BOUNDF, -BOUNDF);
      dt[j] = fmaf(z, cf[j].w, cf[j].y);
    }
    const float prod = ((dt[0] * dt[1]) * (dt[2] * dt[3])) *
                       ((dt[4] * dt[5]) * (dt[6] * dt[7]));

    // non-temporal stores: lane-interleaved => every line fully covered;
    // skip L3 allocation so the write stream doesn't evict x.
    {
      f32x4 v0 = {yv[0], yv[1], yv[2], yv[3]};
      f32x4 v1 = {yv[4], yv[5], yv[6], yv[7]};
      __builtin_nontemporal_store(v0, &out4[2 * t]);
      __builtin_nontemporal_store(v1, &out4[2 * t + 1]);
    }

    const float full = prod * __shfl_xor(prod, 1);
    const float res  = hh ? (aps + __logf(full)) : (aps * full);
    __builtin_nontemporal_store(res, &out[np16 + hh * npts + p]);

    if (!hasB) break;
    t = tB; a0 = b0; a1 = b1; aps = bps;
    tB = tC; hasB = hasC; b0 = c0; b1 = c1; bps = cps;
  }
}

extern "C" void kernel_launch(void* const* d_in, const int* in_sizes, int n_in,
                              void* d_out, int out_size, void* d_ws, size_t ws_size,
                              hipStream_t stream) {
  const float* x    = (const float*)d_in[0];
  const float* pdj  = (const float*)d_in[1];
  const float* sldj = (const float*)d_in[2];
  const float* lp   = (const float*)d_in[3];
  const float* mesh = (const float*)d_in[4];
  float* out = (float*)d_out;

  const int npts   = in_sizes[0] / DIM;
  const int npairs = npts * 2;
  const int block  = 256;
  int grid = 2048;
  const int needed = (npairs + block - 1) / block;
  if (needed < grid) grid = needed;

  hipLaunchKernelGGL(nll_kernel, dim3(grid), dim3(block), 0, stream,
                     x, pdj, sldj, lp, mesh, out, npts, npairs);
}

// Round 14
// 32.466 us; speedup vs baseline: 1.1676x; 1.1676x over previous
//
#include <hip/hip_runtime.h>
#include <math.h>
#include <stdint.h>

// NonLinearLayer: piecewise-quadratic CDF flow on a geometric mesh.
// x:(N,16) f32, pdj:(N,1), sldj:(N,1), log_p:(63,16), mesh_norm:(65,), elmt_size:(64,)
// out = concat(x_out (N*16), pdj_out (N), sldj_out (N))
//
// R14: ONE TASK PER THREAD, fused setup. R11 showed the no-loop main kernel is
// the only structure that cut rocprof dur (44 vs 47-51us): HW block refill
// gives each wave an immediate x-load at wave start (deep natural MLP), no
// 4-deep serial grid-stride chains, no occupancy sawtooth. R11 lost only to
// its serialized 1-block setup dispatch — here setup is fused per-block and
// cheapened: block=512 (8 waves -> 2 dims/wave scan, half the serial chain),
// inputs read straight from global (L2-resident), ONE barrier.
// Main x/pdj loads issue in source BEFORE setup (independent of LDS) so they
// can hide under setup; sentinel bins keep the body branch-free (R8 tile).

namespace {
constexpr int DIM = 16;
constexpr int ME  = 64;
constexpr float BOUNDF = 50.0f;
// K1 = 0.2/one_step = 0.02*(1.2^32-1);  INV_L2R = 1/log2(1.2)
constexpr float K1      = 6.8164378f;
constexpr float INV_L2R = 3.8017840f;
constexpr int NBIN = 66;                        // sentinel 0, real 1..64, sentinel 65
constexpr int ROWF = 68;                        // floats per row: 16 dims * 4 + pad
constexpr int COEF_FLOATS = NBIN * ROWF;        // 4488 floats = 17952 B
constexpr int BLOCK = 512;
}

__global__ __launch_bounds__(BLOCK) void nll_kernel(
    const float* __restrict__ x,
    const float* __restrict__ pdj,
    const float* __restrict__ sldj,
    const float* __restrict__ log_p,
    const float* __restrict__ mesh_norm,
    float* __restrict__ out,
    int npts, int npairs)
{
  __shared__ __align__(16) float co[COEF_FLOATS];

  const int tid  = threadIdx.x;
  const int wv   = tid >> 6;        // 0..7
  const int lane = tid & 63;

  const int t = blockIdx.x * BLOCK + tid;
  const bool live = t < npairs;

  // ---- main-body loads first: independent of setup, can hide under it ----
  const float4* __restrict__ x4 = reinterpret_cast<const float4*>(x);
  float4 xa, xb;
  float ps = 0.f;
  if (live) {
    xa = x4[2 * t];
    xb = x4[2 * t + 1];
    ps = (t & 1) ? sldj[t >> 1] : pdj[t >> 1];
  }

  // ---- setup: 2 dims per wave, direct global reads, one barrier ----
  {
    const float mj  = mesh_norm[lane];
    const float mj1 = mesh_norm[lane + 1];
    const float mj2 = mesh_norm[(lane + 2 > ME) ? ME : (lane + 2)];
    const float es0 = mesh_norm[1];            // mesh_norm[0] == 0
    const float h = mj1 - mj;
#pragma unroll
    for (int i = 0; i < 2; ++i) {
      const int d = 2 * wv + i;
      const float ep = (lane < 63) ? __expf(log_p[lane * DIM + d]) : 0.f;
      float ss = (lane < 63) ? ep * (mj2 - mj) : 0.f;
      ss += __shfl_xor(ss, 1);  ss += __shfl_xor(ss, 2);  ss += __shfl_xor(ss, 4);
      ss += __shfl_xor(ss, 8);  ss += __shfl_xor(ss, 16); ss += __shfl_xor(ss, 32);
      const float scale = (1.0f - es0) / (0.5f * ss);
      const float cur = (lane < 63) ? ep * scale : 1.0f;   // pdf_norm[lane+1]
      float prev = __shfl_up(cur, 1);                       // pdf_norm[lane]
      if (lane == 0) prev = 1.0f;
      const float cell = (prev + cur) * 0.5f * h;
      float v = cell, o;
      o = __shfl_up(v, 1);  if (lane >= 1)  v += o;
      o = __shfl_up(v, 2);  if (lane >= 2)  v += o;
      o = __shfl_up(v, 4);  if (lane >= 4)  v += o;
      o = __shfl_up(v, 8);  if (lane >= 8)  v += o;
      o = __shfl_up(v, 16); if (lane >= 16) v += o;
      o = __shfl_up(v, 32); if (lane >= 32) v += o;
      const float F = v - cell;                             // exclusive prefix = F_ref[lane]
      const float A = 0.5f * (cur - prev) / h;
      const float B = fmaf(-(A + A), mj, prev);
      const float D = fmaf(mj, fmaf(mj, A, -prev), F);
      *reinterpret_cast<float4*>(&co[(lane + 1) * ROWF + 4 * d]) =
          make_float4(A, B, D, A + A);
    }
    // sentinel rows 0 and 65: (A,B,D,2A) = (0,1,0,0) -> y=xn, dt=1 exactly
    if (tid < 32) {
      const int row = (tid >> 4) ? (NBIN - 1) : 0;
      const int d = tid & 15;
      *reinterpret_cast<float4*>(&co[row * ROWF + 4 * d]) =
          make_float4(0.f, 1.f, 0.f, 0.f);
    }
  }
  __syncthreads();

  if (!live) return;

  // ---- one half-point (8 dims): R8's verified tile ----
  float4* __restrict__ out4 = reinterpret_cast<float4*>(out);
  const int np16 = npts * DIM;
  const int p  = t >> 1;
  const int hh = t & 1;                       // half: dims hh*8 .. hh*8+7
  const int dbase = hh << 5;                  // float offset of dim block in a row
  const float vals[8] = {xa.x, xa.y, xa.z, xa.w, xb.x, xb.y, xb.z, xb.w};

  float xn[8];
  int   idx[8];
#pragma unroll
  for (int j = 0; j < 8; ++j) {
    const float val = vals[j];
    xn[j] = fmaf(val, 0.01f, 0.5f);
    const float u = fmaf(fabsf(val), K1, 1.0f);
    const float n = __log2f(u) * INV_L2R;
    int k = 32 + (int)ceilf(copysignf(n, val));   // searchsorted k (analytic)
    k = k < 0 ? 0 : (k > NBIN - 1 ? NBIN - 1 : k);
    idx[j] = k * ROWF + dbase + (j << 2);
  }

  float4 cf[8];
#pragma unroll
  for (int j = 0; j < 8; ++j)
    cf[j] = *reinterpret_cast<const float4*>(&co[idx[j]]);

  float yv[8], dt[8];
#pragma unroll
  for (int j = 0; j < 8; ++j) {
    const float z = xn[j];
    yv[j] = fmaf(fmaf(z, fmaf(z, cf[j].x, cf[j].y), cf[j].z), 2.0f * BOUNDF, -BOUNDF);
    dt[j] = fmaf(z, cf[j].w, cf[j].y);
  }
  const float prod = ((dt[0] * dt[1]) * (dt[2] * dt[3])) *
                     ((dt[4] * dt[5]) * (dt[6] * dt[7]));

  out4[2 * t]     = make_float4(yv[0], yv[1], yv[2], yv[3]);
  out4[2 * t + 1] = make_float4(yv[4], yv[5], yv[6], yv[7]);

  const float full = prod * __shfl_xor(prod, 1);
  const float res  = hh ? (ps + __logf(full)) : (ps * full);
  out[np16 + hh * npts + p] = res;
}

extern "C" void kernel_launch(void* const* d_in, const int* in_sizes, int n_in,
                              void* d_out, int out_size, void* d_ws, size_t ws_size,
                              hipStream_t stream) {
  const float* x    = (const float*)d_in[0];
  const float* pdj  = (const float*)d_in[1];
  const float* sldj = (const float*)d_in[2];
  const float* lp   = (const float*)d_in[3];
  const float* mesh = (const float*)d_in[4];
  float* out = (float*)d_out;

  const int npts   = in_sizes[0] / DIM;
  const int npairs = npts * 2;
  const int grid   = (npairs + BLOCK - 1) / BLOCK;    // 4096 @ 1M points

  hipLaunchKernelGGL(nll_kernel, dim3(grid), dim3(BLOCK), 0, stream,
                     x, pdj, sldj, lp, mesh, out, npts, npairs);
}